// Round 3
// baseline (545.145 us; speedup 1.0000x reference)
//
#include <hip/hip_runtime.h>
#include <hip/hip_bf16.h>
#include <stdint.h>

#define BATCH 4
#define NPTS  1024
#define CIN   512
#define NS    32
#define P_TOT (BATCH*NPTS*NS)      /* 131072 */
#define K1    544                  /* 512 + 32 tail */
#define CO    512
#define RADIUS_F 0.05f
#define HMIN_F  (-0.02f)
#define HMAX_F  (0.04f)

typedef __attribute__((ext_vector_type(8))) short short8;
typedef __attribute__((ext_vector_type(4))) float f32x4;

__device__ __forceinline__ unsigned short f2bf(float f) {
  unsigned int x = __float_as_uint(f);
  x = x + 0x7fffu + ((x >> 16) & 1u);   // RNE
  return (unsigned short)(x >> 16);
}
__device__ __forceinline__ float bf2f(unsigned short u) {
  return __uint_as_float(((unsigned int)u) << 16);
}
__device__ __forceinline__ void load_lds16(const void* g, void* l) {
  __builtin_amdgcn_global_load_lds((const __attribute__((address_space(1))) void*)g,
                                   (__attribute__((address_space(3))) void*)l, 16, 0, 0);
}

// ---------------- cylinder query: idx + local coords into tail[p][0..31] ----
__global__ void cyl_query_kernel(const float* __restrict__ xyz,
                                 const float* __restrict__ rot,
                                 int* __restrict__ idxout,
                                 unsigned short* __restrict__ tail) {
  int bm = blockIdx.x;             // b*1024 + m
  int b = bm >> 10;
  int lane = threadIdx.x;          // 64 threads = 1 wave
  const float* ctr = xyz + (size_t)bm * 3;
  float cx = ctr[0], cy = ctr[1], cz = ctr[2];
  const float* R = rot + (size_t)bm * 9;
  float r00=R[0],r01=R[1],r02=R[2],r10=R[3],r11=R[4],r12=R[5],r20=R[6],r21=R[7],r22=R[8];
  __shared__ int sidx[32];
  int taken = 0;
  for (int base = 0; base < NPTS && taken < NS; base += 64) {
    int n = base + lane;
    const float* p = xyz + ((size_t)b * NPTS + n) * 3;
    float dx = p[0]-cx, dy = p[1]-cy, dz = p[2]-cz;
    float rx = dx*r00 + dy*r10 + dz*r20;
    float ry = dx*r01 + dy*r11 + dz*r21;
    float rz = dx*r02 + dy*r12 + dz*r22;
    bool ok = (ry*ry + rz*rz < RADIUS_F*RADIUS_F) && (rx > HMIN_F) && (rx < HMAX_F);
    unsigned long long bal = __ballot(ok);
    if (ok) {
      int slot = taken + __popcll(bal & ((1ull << lane) - 1ull));
      if (slot < NS) sidx[slot] = n;
    }
    taken += __popcll(bal);
  }
  __syncthreads();
  int filled = taken < NS ? taken : NS;
  if (lane < NS) {
    int nsel = (lane < filled) ? sidx[lane] : sidx[0];
    size_t p0 = (size_t)bm * NS + lane;
    idxout[p0] = nsel;
    const float* pn = xyz + ((size_t)b * NPTS + nsel) * 3;
    float dx = pn[0]-cx, dy = pn[1]-cy, dz = pn[2]-cz;
    const float inv = 1.0f / RADIUS_F;
    float rx = (dx*r00 + dy*r10 + dz*r20) * inv;
    float ry = (dx*r01 + dy*r11 + dz*r21) * inv;
    float rz = (dx*r02 + dy*r12 + dz*r22) * inv;
    unsigned short* row = tail + p0 * 32;
    row[0] = f2bf(rx); row[1] = f2bf(ry); row[2] = f2bf(rz);
    #pragma unroll
    for (int k = 3; k < 32; ++k) row[k] = 0;
  }
}

// ---------------- transpose feats (B,C,N) fp32 -> (B,N,C) bf16 --------------
__global__ void transpose_feats(const float* __restrict__ feats,
                                unsigned short* __restrict__ featsT) {
  __shared__ float tile[64][65];
  int b = blockIdx.z, cb = blockIdx.y, nb = blockIdx.x;
  int t = threadIdx.x, tr = t >> 6, tc = t & 63;
  #pragma unroll
  for (int j = 0; j < 16; ++j) {
    int c = cb*64 + j*4 + tr;
    tile[j*4+tr][tc] = feats[((size_t)b*CIN + c)*NPTS + nb*64 + tc];
  }
  __syncthreads();
  #pragma unroll
  for (int j = 0; j < 16; ++j) {
    int n = nb*64 + j*4 + tr;
    featsT[((size_t)b*NPTS + n)*CIN + cb*64 + tc] = f2bf(tile[tc][j*4+tr]);
  }
}

// ---------------- weight conversion -----------------------------------------
__global__ void build_w1(const float* __restrict__ W1, unsigned short* __restrict__ w1b) {
  int i = blockIdx.x*256 + threadIdx.x;
  if (i >= CO*K1) return;
  int o = i / K1, k = i % K1;
  float v = 0.f;
  if (k < 512) v = W1[o*515 + 3 + k];
  else if (k < 515) v = W1[o*515 + (k - 512)];
  w1b[i] = f2bf(v);
}
__global__ void build_w2(const float* __restrict__ W2, unsigned short* __restrict__ w2b) {
  int i = blockIdx.x*256 + threadIdx.x;
  if (i < CO*CIN) w2b[i] = f2bf(W2[i]);
}

// ============ GEMM1: gathered A (fT via idx, tail) x W1^T ====================
// Swapped operands: af = W-frags (o = MFMA rows), bf = X-frags (p = MFMA cols).
// acc[mi][ni]: o = o0 + wc*64 + mi*16 + l4*4 + j ; p = p0 + wr*64 + ni*16 + l15
__global__ __launch_bounds__(256, 2) void gemm1_kernel(
    const unsigned short* __restrict__ fT,
    const unsigned short* __restrict__ tail,
    const int* __restrict__ idx,
    const unsigned short* __restrict__ Bw,    // (512, 544)
    unsigned short* __restrict__ C,           // (P, 512) raw pre-BN
    float* __restrict__ sums)
{
  __shared__ unsigned short Xs[2][128*64];
  __shared__ unsigned short Ws[2][128*64];
  int bx = blockIdx.x;
  int o0 = (bx & 3) * 128;
  size_t p0 = (size_t)(bx >> 2) * 128;
  int t = threadIdx.x;
  int w = t >> 6, lane = t & 63;
  int wr = w >> 1, wc = w & 1;
  int l15 = lane & 15, l4 = lane >> 4;

  // ---- staging geometry: BK=64 tiles, 4 passes x (row = q*32 + t>>3, slot = t&7)
  int slot = t & 7;
  const unsigned short* aSrc[4];
  const unsigned short* bSrc[4];
  #pragma unroll
  for (int q = 0; q < 4; ++q) {
    int r = q*32 + (t >> 3);
    size_t p = p0 + r;
    int b = (int)(p >> 15);
    int n = idx[p];
    int sl = slot ^ (r & 7);                       // pre-swizzled source slot
    aSrc[q] = fT + (((size_t)b << 10) + n) * 512 + sl*8;
    bSrc[q] = Bw + (size_t)(o0 + r) * 544 + sl*8;
  }
  // tail tile (BK=32): 2 passes x (row = q*64 + t>>2, slot4 = t&3)
  const unsigned short* tSrcA[2];
  const unsigned short* tSrcB[2];
  {
    int s4 = t & 3;
    #pragma unroll
    for (int q = 0; q < 2; ++q) {
      int r = q*64 + (t >> 2);
      int sl = s4 ^ ((r >> 1) & 3);
      tSrcA[q] = tail + (p0 + r) * 32 + sl*8;
      tSrcB[q] = Bw + (size_t)(o0 + r) * 544 + 512 + sl*8;
    }
  }

  f32x4 acc[4][4];
  f32x4 zf = {0.f, 0.f, 0.f, 0.f};
  #pragma unroll
  for (int mi = 0; mi < 4; ++mi)
    #pragma unroll
    for (int ni = 0; ni < 4; ++ni) acc[mi][ni] = zf;

  int xm = l15 & 7;         // read-side XOR (row&7 == l15&7 for 16-aligned bases)
  int xmT = (l15 >> 1) & 3; // tail read-side XOR

  // prologue: stage tile 0 into buf 0
  #pragma unroll
  for (int q = 0; q < 4; ++q) {
    load_lds16(aSrc[q], (char*)&Xs[0][0] + q*4096 + t*16);
    load_lds16(bSrc[q], (char*)&Ws[0][0] + q*4096 + t*16);
  }
  __syncthreads();

  int cur = 0;
  for (int kt = 0; kt < 8; ++kt) {
    // stage next tile into buf^1 (issue first; latency hides under compute)
    if (kt < 7) {
      #pragma unroll
      for (int q = 0; q < 4; ++q) {
        load_lds16(aSrc[q] + (kt+1)*64, (char*)&Xs[cur^1][0] + q*4096 + t*16);
        load_lds16(bSrc[q] + (kt+1)*64, (char*)&Ws[cur^1][0] + q*4096 + t*16);
      }
    } else {
      #pragma unroll
      for (int q = 0; q < 2; ++q) {
        load_lds16(tSrcA[q], (char*)&Xs[cur^1][0] + q*4096 + t*16);
        load_lds16(tSrcB[q], (char*)&Ws[cur^1][0] + q*4096 + t*16);
      }
    }
    // compute current tile (BK=64: 2 k-steps of 32)
    #pragma unroll
    for (int kk = 0; kk < 2; ++kk) {
      int cA = ((kk*4 + l4) ^ xm) * 8;
      short8 af[4], bfr[4];
      #pragma unroll
      for (int mi = 0; mi < 4; ++mi)
        af[mi] = *(const short8*)(&Ws[cur][(wc*64 + mi*16 + l15)*64 + cA]);
      #pragma unroll
      for (int ni = 0; ni < 4; ++ni)
        bfr[ni] = *(const short8*)(&Xs[cur][(wr*64 + ni*16 + l15)*64 + cA]);
      #pragma unroll
      for (int mi = 0; mi < 4; ++mi)
        #pragma unroll
        for (int ni = 0; ni < 4; ++ni)
          acc[mi][ni] = __builtin_amdgcn_mfma_f32_16x16x32_bf16(af[mi], bfr[ni], acc[mi][ni], 0, 0, 0);
    }
    __syncthreads();   // drains vmcnt(0)+lgkmcnt(0): next buf ready
    cur ^= 1;
  }
  // tail compute (BK=32)
  {
    int cT = (l4 ^ xmT) * 8;
    short8 af[4], bfr[4];
    #pragma unroll
    for (int mi = 0; mi < 4; ++mi)
      af[mi] = *(const short8*)(&Ws[cur][(wc*64 + mi*16 + l15)*32 + cT]);
    #pragma unroll
    for (int ni = 0; ni < 4; ++ni)
      bfr[ni] = *(const short8*)(&Xs[cur][(wr*64 + ni*16 + l15)*32 + cT]);
    #pragma unroll
    for (int mi = 0; mi < 4; ++mi)
      #pragma unroll
      for (int ni = 0; ni < 4; ++ni)
        acc[mi][ni] = __builtin_amdgcn_mfma_f32_16x16x32_bf16(af[mi], bfr[ni], acc[mi][ni], 0, 0, 0);
  }

  // ---- per-channel stats: sum over p (ni frags + 16-lane groups) -----------
  #pragma unroll
  for (int mi = 0; mi < 4; ++mi) {
    float ps[4] = {0.f,0.f,0.f,0.f}, qs[4] = {0.f,0.f,0.f,0.f};
    #pragma unroll
    for (int ni = 0; ni < 4; ++ni)
      #pragma unroll
      for (int j = 0; j < 4; ++j) { float v = acc[mi][ni][j]; ps[j] += v; qs[j] += v*v; }
    #pragma unroll
    for (int j = 0; j < 4; ++j) {
      #pragma unroll
      for (int m = 1; m < 16; m <<= 1) {
        ps[j] += __shfl_xor(ps[j], m);
        qs[j] += __shfl_xor(qs[j], m);
      }
    }
    if (l15 == 0) {
      int o = o0 + wc*64 + mi*16 + l4*4;
      #pragma unroll
      for (int j = 0; j < 4; ++j) {
        atomicAdd(&sums[o+j], ps[j]);
        atomicAdd(&sums[512+o+j], qs[j]);
      }
    }
  }
  // ---- C store: 4 contiguous o per lane -> ushort4 -------------------------
  #pragma unroll
  for (int ni = 0; ni < 4; ++ni) {
    size_t p = p0 + wr*64 + ni*16 + l15;
    #pragma unroll
    for (int mi = 0; mi < 4; ++mi) {
      int o = o0 + wc*64 + mi*16 + l4*4;
      ushort4 v = make_ushort4(f2bf(acc[mi][ni][0]), f2bf(acc[mi][ni][1]),
                               f2bf(acc[mi][ni][2]), f2bf(acc[mi][ni][3]));
      *(ushort4*)(C + p*CO + o) = v;
    }
  }
}

__global__ void finalize_kernel(const float* __restrict__ sums,
                                const float* __restrict__ g,
                                const float* __restrict__ bia,
                                float* __restrict__ ss) {
  int c = blockIdx.x*256 + threadIdx.x;
  if (c >= 512) return;
  const float invN = 1.f / (float)P_TOT;
  float mean = sums[c] * invN;
  float var  = sums[512+c] * invN - mean*mean;
  float sc = g[c] * rsqrtf(var + 1e-5f);
  ss[c] = sc;
  ss[512+c] = bia[c] - mean*sc;
}

// ============ GEMM2: A = relu(affine(h1_raw)) fused in staging ===============
__global__ __launch_bounds__(256, 2) void gemm2_kernel(
    const unsigned short* __restrict__ h1,    // (P, 512) raw
    const unsigned short* __restrict__ Bw,    // (512, 512)
    const float* __restrict__ ss,             // BN1 scale/shift
    float* __restrict__ sums,                 // BN2 stats
    float* __restrict__ pmax,                 // (4096, 512)
    float* __restrict__ pmin)
{
  __shared__ unsigned short Xs[2][128*64];
  __shared__ unsigned short Ws[2][128*64];
  int bx = blockIdx.x;
  int o0 = (bx & 3) * 128;
  size_t p0 = (size_t)(bx >> 2) * 128;
  int t = threadIdx.x;
  int w = t >> 6, lane = t & 63;
  int wr = w >> 1, wc = w & 1;
  int l15 = lane & 15, l4 = lane >> 4;

  int slot = t & 7;
  const unsigned short* aSrc[4];   // unswizzled (reg-staged)
  const unsigned short* bSrc[4];   // pre-swizzled source for gload_lds
  int aOff[4];                     // swizzled LDS element offsets for ds_write
  #pragma unroll
  for (int q = 0; q < 4; ++q) {
    int r = q*32 + (t >> 3);
    aSrc[q] = h1 + (p0 + r) * 512 + slot*8;
    int sl = slot ^ (r & 7);
    bSrc[q] = Bw + (size_t)(o0 + r) * 512 + sl*8;
    aOff[q] = r*64 + sl*8;
  }

  f32x4 acc[4][4];
  f32x4 zf = {0.f, 0.f, 0.f, 0.f};
  #pragma unroll
  for (int mi = 0; mi < 4; ++mi)
    #pragma unroll
    for (int ni = 0; ni < 4; ++ni) acc[mi][ni] = zf;

  int xm = l15 & 7;
  uint4 areg[4];

  // transform helper data: channels for this thread at tile kt: c0 = kt*64 + slot*8
  // prologue: tile 0
  #pragma unroll
  for (int q = 0; q < 4; ++q) {
    load_lds16(bSrc[q], (char*)&Ws[0][0] + q*4096 + t*16);
    areg[q] = *(const uint4*)(aSrc[q]);
  }
  {
    int c0 = slot*8;
    float4 scA = *(const float4*)(ss + c0);
    float4 scB = *(const float4*)(ss + c0 + 4);
    float4 shA = *(const float4*)(ss + 512 + c0);
    float4 shB = *(const float4*)(ss + 512 + c0 + 4);
    float sc[8] = {scA.x,scA.y,scA.z,scA.w,scB.x,scB.y,scB.z,scB.w};
    float sh[8] = {shA.x,shA.y,shA.z,shA.w,shB.x,shB.y,shB.z,shB.w};
    #pragma unroll
    for (int q = 0; q < 4; ++q) {
      unsigned int wv[4] = {areg[q].x, areg[q].y, areg[q].z, areg[q].w};
      unsigned int rv[4];
      #pragma unroll
      for (int j = 0; j < 4; ++j) {
        float f0 = fmaxf(fmaf(bf2f((unsigned short)(wv[j] & 0xffffu)), sc[2*j],   sh[2*j]),   0.f);
        float f1 = fmaxf(fmaf(bf2f((unsigned short)(wv[j] >> 16)),     sc[2*j+1], sh[2*j+1]), 0.f);
        rv[j] = (unsigned int)f2bf(f0) | ((unsigned int)f2bf(f1) << 16);
      }
      *(uint4*)(&Xs[0][aOff[q]]) = make_uint4(rv[0], rv[1], rv[2], rv[3]);
    }
  }
  __syncthreads();

  int cur = 0;
  for (int kt = 0; kt < 8; ++kt) {
    // issue next-tile loads first
    if (kt < 7) {
      #pragma unroll
      for (int q = 0; q < 4; ++q) {
        load_lds16(bSrc[q] + (kt+1)*64, (char*)&Ws[cur^1][0] + q*4096 + t*16);
        areg[q] = *(const uint4*)(aSrc[q] + (kt+1)*64);
      }
    }
    // compute current tile
    #pragma unroll
    for (int kk = 0; kk < 2; ++kk) {
      int cA = ((kk*4 + l4) ^ xm) * 8;
      short8 af[4], bfr[4];
      #pragma unroll
      for (int mi = 0; mi < 4; ++mi)
        af[mi] = *(const short8*)(&Ws[cur][(wc*64 + mi*16 + l15)*64 + cA]);
      #pragma unroll
      for (int ni = 0; ni < 4; ++ni)
        bfr[ni] = *(const short8*)(&Xs[cur][(wr*64 + ni*16 + l15)*64 + cA]);
      #pragma unroll
      for (int mi = 0; mi < 4; ++mi)
        #pragma unroll
        for (int ni = 0; ni < 4; ++ni)
          acc[mi][ni] = __builtin_amdgcn_mfma_f32_16x16x32_bf16(af[mi], bfr[ni], acc[mi][ni], 0, 0, 0);
    }
    // transform + swizzled ds_write of next A tile
    if (kt < 7) {
      int c0 = (kt+1)*64 + slot*8;
      float4 scA = *(const float4*)(ss + c0);
      float4 scB = *(const float4*)(ss + c0 + 4);
      float4 shA = *(const float4*)(ss + 512 + c0);
      float4 shB = *(const float4*)(ss + 512 + c0 + 4);
      float sc[8] = {scA.x,scA.y,scA.z,scA.w,scB.x,scB.y,scB.z,scB.w};
      float sh[8] = {shA.x,shA.y,shA.z,shA.w,shB.x,shB.y,shB.z,shB.w};
      #pragma unroll
      for (int q = 0; q < 4; ++q) {
        unsigned int wv[4] = {areg[q].x, areg[q].y, areg[q].z, areg[q].w};
        unsigned int rv[4];
        #pragma unroll
        for (int j = 0; j < 4; ++j) {
          float f0 = fmaxf(fmaf(bf2f((unsigned short)(wv[j] & 0xffffu)), sc[2*j],   sh[2*j]),   0.f);
          float f1 = fmaxf(fmaf(bf2f((unsigned short)(wv[j] >> 16)),     sc[2*j+1], sh[2*j+1]), 0.f);
          rv[j] = (unsigned int)f2bf(f0) | ((unsigned int)f2bf(f1) << 16);
        }
        *(uint4*)(&Xs[cur^1][aOff[q]]) = make_uint4(rv[0], rv[1], rv[2], rv[3]);
      }
    }
    __syncthreads();
    cur ^= 1;
  }

  // ---- BN2 stats -----------------------------------------------------------
  #pragma unroll
  for (int mi = 0; mi < 4; ++mi) {
    float ps[4] = {0.f,0.f,0.f,0.f}, qs[4] = {0.f,0.f,0.f,0.f};
    #pragma unroll
    for (int ni = 0; ni < 4; ++ni)
      #pragma unroll
      for (int j = 0; j < 4; ++j) { float v = acc[mi][ni][j]; ps[j] += v; qs[j] += v*v; }
    #pragma unroll
    for (int j = 0; j < 4; ++j) {
      #pragma unroll
      for (int m = 1; m < 16; m <<= 1) {
        ps[j] += __shfl_xor(ps[j], m);
        qs[j] += __shfl_xor(qs[j], m);
      }
    }
    if (l15 == 0) {
      int o = o0 + wc*64 + mi*16 + l4*4;
      #pragma unroll
      for (int j = 0; j < 4; ++j) {
        atomicAdd(&sums[o+j], ps[j]);
        atomicAdd(&sums[512+o+j], qs[j]);
      }
    }
  }
  // ---- max/min pool over S=32 (p-groups: ni pairs x 16 lanes) --------------
  #pragma unroll
  for (int mi = 0; mi < 4; ++mi) {
    #pragma unroll
    for (int h = 0; h < 2; ++h) {
      float mx[4], mn[4];
      #pragma unroll
      for (int j = 0; j < 4; ++j) { mx[j] = -3.4e38f; mn[j] = 3.4e38f; }
      #pragma unroll
      for (int ni = 2*h; ni < 2*h + 2; ++ni)
        #pragma unroll
        for (int j = 0; j < 4; ++j) {
          float v = acc[mi][ni][j];
          mx[j] = fmaxf(mx[j], v); mn[j] = fminf(mn[j], v);
        }
      #pragma unroll
      for (int j = 0; j < 4; ++j) {
        #pragma unroll
        for (int m = 1; m < 16; m <<= 1) {
          mx[j] = fmaxf(mx[j], __shfl_xor(mx[j], m));
          mn[j] = fminf(mn[j], __shfl_xor(mn[j], m));
        }
      }
      if (l15 == 0) {
        size_t seed = (p0 >> 5) + wr*2 + h;
        int o = o0 + wc*64 + mi*16 + l4*4;
        *(float4*)(pmax + seed*512 + o) = make_float4(mx[0], mx[1], mx[2], mx[3]);
        *(float4*)(pmin + seed*512 + o) = make_float4(mn[0], mn[1], mn[2], mn[3]);
      }
    }
  }
}

// ---------------- final: affine+relu on pooled, transpose to (B,512,M) ------
__global__ void final_transpose(const float* __restrict__ pmax,
                                const float* __restrict__ pmin,
                                const float* __restrict__ ss,
                                float* __restrict__ out) {
  __shared__ float tile[64][65];
  int b = blockIdx.z, ob = blockIdx.y, mb = blockIdx.x;
  int t = threadIdx.x, tr = t >> 6, tc = t & 63;
  #pragma unroll
  for (int j = 0; j < 16; ++j) {
    int m = mb*64 + j*4 + tr;
    int o = ob*64 + tc;
    float sc = ss[o], sh = ss[512+o];
    size_t pi = (((size_t)b << 10) + m)*512 + o;
    float v = (sc >= 0.f) ? pmax[pi] : pmin[pi];
    tile[j*4+tr][tc] = fmaxf(fmaf(v, sc, sh), 0.f);
  }
  __syncthreads();
  #pragma unroll
  for (int j = 0; j < 16; ++j) {
    int o = ob*64 + j*4 + tr;
    out[((size_t)b*512 + o)*1024 + mb*64 + tc] = tile[tc][j*4+tr];
  }
}

extern "C" void kernel_launch(void* const* d_in, const int* in_sizes, int n_in,
                              void* d_out, int out_size, void* d_ws, size_t ws_size,
                              hipStream_t stream) {
  const float* xyz   = (const float*)d_in[0];
  const float* feats = (const float*)d_in[1];
  const float* rot   = (const float*)d_in[2];
  const float* W1    = (const float*)d_in[3];
  const float* g1    = (const float*)d_in[4];
  const float* b1    = (const float*)d_in[5];
  const float* W2    = (const float*)d_in[6];
  const float* g2    = (const float*)d_in[7];
  const float* b2    = (const float*)d_in[8];
  float* out = (float*)d_out;
  char* wsb = (char*)d_ws;

  const size_t OFF_IDX    = 0;
  const size_t OFF_TAIL   = OFF_IDX    + (size_t)P_TOT*4;
  const size_t OFF_FEATST = OFF_TAIL   + (size_t)P_TOT*32*2;
  const size_t OFF_W1B    = OFF_FEATST + (size_t)BATCH*NPTS*CIN*2;
  const size_t OFF_W2B    = OFF_W1B    + (size_t)CO*K1*2;
  const size_t OFF_STATS  = OFF_W2B    + (size_t)CO*CIN*2;
  const size_t OFF_PMAX   = OFF_STATS  + 16384;
  const size_t OFF_PMIN   = OFF_PMAX   + (size_t)BATCH*NPTS*CO*4;
  const size_t OFF_H1     = OFF_PMIN   + (size_t)BATCH*NPTS*CO*4;
  const size_t WS_NEED    = OFF_H1     + (size_t)P_TOT*CO*2;   // ~158 MiB (proven fit)

  if (ws_size < WS_NEED) return;   // diagnostic guard

  int* idx             = (int*)(wsb + OFF_IDX);
  unsigned short* tail = (unsigned short*)(wsb + OFF_TAIL);
  unsigned short* fT   = (unsigned short*)(wsb + OFF_FEATST);
  unsigned short* w1b  = (unsigned short*)(wsb + OFF_W1B);
  unsigned short* w2b  = (unsigned short*)(wsb + OFF_W2B);
  float* stats         = (float*)(wsb + OFF_STATS);
  float* sums1 = stats;
  float* ss1   = stats + 1024;
  float* sums2 = stats + 2048;
  float* ss2   = stats + 3072;
  float* pmax          = (float*)(wsb + OFF_PMAX);
  float* pmin          = (float*)(wsb + OFF_PMIN);
  unsigned short* h1   = (unsigned short*)(wsb + OFF_H1);

  hipMemsetAsync(stats, 0, 16384, stream);

  transpose_feats<<<dim3(NPTS/64, CIN/64, BATCH), 256, 0, stream>>>(feats, fT);
  cyl_query_kernel<<<BATCH*NPTS, 64, 0, stream>>>(xyz, rot, idx, tail);
  build_w1<<<(CO*K1 + 255)/256, 256, 0, stream>>>(W1, w1b);
  build_w2<<<(CO*CIN + 255)/256, 256, 0, stream>>>(W2, w2b);

  gemm1_kernel<<<(P_TOT/128)*4, 256, 0, stream>>>(fT, tail, idx, w1b, h1, sums1);
  finalize_kernel<<<2, 256, 0, stream>>>(sums1, g1, b1, ss1);

  gemm2_kernel<<<(P_TOT/128)*4, 256, 0, stream>>>(h1, w2b, ss1, sums2, pmax, pmin);
  finalize_kernel<<<2, 256, 0, stream>>>(sums2, g2, b2, ss2);

  final_transpose<<<dim3(NPTS/64, CO/64, BATCH), 256, 0, stream>>>(pmax, pmin, ss2, out);
}

// Round 4
// 516.069 us; speedup vs baseline: 1.0563x; 1.0563x over previous
//
#include <hip/hip_runtime.h>
#include <hip/hip_bf16.h>
#include <stdint.h>

#define BATCH 4
#define NPTS  1024
#define CIN   512
#define NS    32
#define P_TOT (BATCH*NPTS*NS)      /* 131072 */
#define K1    544                  /* 512 + 32 tail */
#define CO    512
#define RADIUS_F 0.05f
#define HMIN_F  (-0.02f)
#define HMAX_F  (0.04f)

typedef __attribute__((ext_vector_type(8))) short short8;
typedef __attribute__((ext_vector_type(4))) float f32x4;

__device__ __forceinline__ unsigned short f2bf(float f) {
  unsigned int x = __float_as_uint(f);
  x = x + 0x7fffu + ((x >> 16) & 1u);   // RNE
  return (unsigned short)(x >> 16);
}
__device__ __forceinline__ float bf2f(unsigned short u) {
  return __uint_as_float(((unsigned int)u) << 16);
}
__device__ __forceinline__ void load_lds16(const void* g, void* l) {
  __builtin_amdgcn_global_load_lds((const __attribute__((address_space(1))) void*)g,
                                   (__attribute__((address_space(3))) void*)l, 16, 0, 0);
}

// ---------------- cylinder query: idx + local coords into tail[p][0..31] ----
__global__ void cyl_query_kernel(const float* __restrict__ xyz,
                                 const float* __restrict__ rot,
                                 int* __restrict__ idxout,
                                 unsigned short* __restrict__ tail) {
  int bm = blockIdx.x;             // b*1024 + m
  int b = bm >> 10;
  int lane = threadIdx.x;          // 64 threads = 1 wave
  const float* ctr = xyz + (size_t)bm * 3;
  float cx = ctr[0], cy = ctr[1], cz = ctr[2];
  const float* R = rot + (size_t)bm * 9;
  float r00=R[0],r01=R[1],r02=R[2],r10=R[3],r11=R[4],r12=R[5],r20=R[6],r21=R[7],r22=R[8];
  __shared__ int sidx[32];
  int taken = 0;
  for (int base = 0; base < NPTS && taken < NS; base += 64) {
    int n = base + lane;
    const float* p = xyz + ((size_t)b * NPTS + n) * 3;
    float dx = p[0]-cx, dy = p[1]-cy, dz = p[2]-cz;
    float rx = dx*r00 + dy*r10 + dz*r20;
    float ry = dx*r01 + dy*r11 + dz*r21;
    float rz = dx*r02 + dy*r12 + dz*r22;
    bool ok = (ry*ry + rz*rz < RADIUS_F*RADIUS_F) && (rx > HMIN_F) && (rx < HMAX_F);
    unsigned long long bal = __ballot(ok);
    if (ok) {
      int slot = taken + __popcll(bal & ((1ull << lane) - 1ull));
      if (slot < NS) sidx[slot] = n;
    }
    taken += __popcll(bal);
  }
  __syncthreads();
  int filled = taken < NS ? taken : NS;
  if (lane < NS) {
    int nsel = (lane < filled) ? sidx[lane] : sidx[0];
    size_t p0 = (size_t)bm * NS + lane;
    idxout[p0] = nsel;
    const float* pn = xyz + ((size_t)b * NPTS + nsel) * 3;
    float dx = pn[0]-cx, dy = pn[1]-cy, dz = pn[2]-cz;
    const float inv = 1.0f / RADIUS_F;
    float rx = (dx*r00 + dy*r10 + dz*r20) * inv;
    float ry = (dx*r01 + dy*r11 + dz*r21) * inv;
    float rz = (dx*r02 + dy*r12 + dz*r22) * inv;
    unsigned short* row = tail + p0 * 32;
    row[0] = f2bf(rx); row[1] = f2bf(ry); row[2] = f2bf(rz);
    #pragma unroll
    for (int k = 3; k < 32; ++k) row[k] = 0;
  }
}

// ---------------- transpose feats (B,C,N) fp32 -> (B,N,C) bf16 --------------
__global__ void transpose_feats(const float* __restrict__ feats,
                                unsigned short* __restrict__ featsT) {
  __shared__ float tile[64][65];
  int b = blockIdx.z, cb = blockIdx.y, nb = blockIdx.x;
  int t = threadIdx.x, tr = t >> 6, tc = t & 63;
  #pragma unroll
  for (int j = 0; j < 16; ++j) {
    int c = cb*64 + j*4 + tr;
    tile[j*4+tr][tc] = feats[((size_t)b*CIN + c)*NPTS + nb*64 + tc];
  }
  __syncthreads();
  #pragma unroll
  for (int j = 0; j < 16; ++j) {
    int n = nb*64 + j*4 + tr;
    featsT[((size_t)b*NPTS + n)*CIN + cb*64 + tc] = f2bf(tile[tc][j*4+tr]);
  }
}

// ---------------- weight conversion -----------------------------------------
__global__ void build_w1(const float* __restrict__ W1, unsigned short* __restrict__ w1b) {
  int i = blockIdx.x*256 + threadIdx.x;
  if (i >= CO*K1) return;
  int o = i / K1, k = i % K1;
  float v = 0.f;
  if (k < 512) v = W1[o*515 + 3 + k];
  else if (k < 515) v = W1[o*515 + (k - 512)];
  w1b[i] = f2bf(v);
}
__global__ void build_w2(const float* __restrict__ W2, unsigned short* __restrict__ w2b) {
  int i = blockIdx.x*256 + threadIdx.x;
  if (i < CO*CIN) w2b[i] = f2bf(W2[i]);
}

// ============ GEMM1: gathered A (fT via idx, tail) x W1^T ====================
// Swapped operands: af = W-frags (o = MFMA rows), bf = X-frags (p = MFMA cols).
// acc[mi][ni]: o = o0 + wc*64 + mi*16 + l4*4 + j ; p = p0 + wr*64 + ni*16 + l15
// LDS swizzle: 4 slots of 16B per 32-elem row; LDS[row][s] = G[row][s ^ ((row>>1)&3)]
__global__ __launch_bounds__(256) void gemm1_kernel(
    const unsigned short* __restrict__ fT,
    const unsigned short* __restrict__ tail,
    const int* __restrict__ idx,
    const unsigned short* __restrict__ Bw,    // (512, 544)
    unsigned short* __restrict__ C,           // (P, 512) raw pre-BN
    float* __restrict__ sums)
{
  __shared__ unsigned short Ws_[128*32];
  __shared__ unsigned short Xs[128*32];
  int bx = blockIdx.x;
  int lg = (bx & 7)*512 + (bx >> 3);          // bijective XCD swizzle (4096%8==0)
  int o0 = (lg & 3) * 128;
  size_t p0 = (size_t)(lg >> 2) * 128;
  int t = threadIdx.x;
  int w = t >> 6, lane = t & 63;
  int wr = w >> 1, wc = w & 1;
  int l15 = lane & 15, l4 = lane >> 4;

  // staging: chunk c = 2w+cc covers rows 16c..16c+15; row = 16c + (lane>>2),
  // dest slot = lane&3; source slot pre-swizzled: sl = (lane&3) ^ ((row>>1)&3)
  int sl = (lane & 3) ^ ((lane >> 3) & 3);
  const unsigned short* xsrc[2];
  const unsigned short* xtl[2];
  const unsigned short* wsrc[2];
  #pragma unroll
  for (int cc = 0; cc < 2; ++cc) {
    int c = 2*w + cc;
    int row = 16*c + (lane >> 2);
    size_t p = p0 + row;
    int b = (int)(p >> 15);
    int n = idx[p];
    xsrc[cc] = fT + (((size_t)b << 10) + n) * 512 + sl*8;
    xtl[cc]  = tail + p * 32 + sl*8;
    wsrc[cc] = Bw + (size_t)(o0 + row) * 544 + sl*8;
  }

  f32x4 acc[4][4];
  f32x4 zf = {0.f, 0.f, 0.f, 0.f};
  #pragma unroll
  for (int mi = 0; mi < 4; ++mi)
    #pragma unroll
    for (int ni = 0; ni < 4; ++ni) acc[mi][ni] = zf;

  int xm = (l15 >> 1) & 3;   // read-side XOR: (row>>1)&3 with 16-aligned bases

  for (int k0 = 0; k0 < K1; k0 += 32) {
    #pragma unroll
    for (int cc = 0; cc < 2; ++cc) {
      int c = 2*w + cc;
      const unsigned short* gX = (k0 < 512) ? (xsrc[cc] + k0) : xtl[cc];
      load_lds16(gX, (char*)Xs + c*1024);
      load_lds16(wsrc[cc] + k0, (char*)Ws_ + c*1024);
    }
    __syncthreads();
    int cA = (l4 ^ xm) * 8;
    short8 af[4], bfr[4];
    #pragma unroll
    for (int mi = 0; mi < 4; ++mi)
      af[mi] = *(const short8*)(Ws_ + (wc*64 + mi*16 + l15)*32 + cA);
    #pragma unroll
    for (int ni = 0; ni < 4; ++ni)
      bfr[ni] = *(const short8*)(Xs + (wr*64 + ni*16 + l15)*32 + cA);
    #pragma unroll
    for (int mi = 0; mi < 4; ++mi)
      #pragma unroll
      for (int ni = 0; ni < 4; ++ni)
        acc[mi][ni] = __builtin_amdgcn_mfma_f32_16x16x32_bf16(af[mi], bfr[ni], acc[mi][ni], 0, 0, 0);
    __syncthreads();
  }

  // ---- per-channel stats: sum over p (ni frags + 16-lane groups) -----------
  #pragma unroll
  for (int mi = 0; mi < 4; ++mi) {
    float ps[4] = {0.f,0.f,0.f,0.f}, qs[4] = {0.f,0.f,0.f,0.f};
    #pragma unroll
    for (int ni = 0; ni < 4; ++ni)
      #pragma unroll
      for (int j = 0; j < 4; ++j) { float v = acc[mi][ni][j]; ps[j] += v; qs[j] += v*v; }
    #pragma unroll
    for (int j = 0; j < 4; ++j) {
      #pragma unroll
      for (int m = 1; m < 16; m <<= 1) {
        ps[j] += __shfl_xor(ps[j], m);
        qs[j] += __shfl_xor(qs[j], m);
      }
    }
    if (l15 == 0) {
      int o = o0 + wc*64 + mi*16 + l4*4;
      #pragma unroll
      for (int j = 0; j < 4; ++j) {
        atomicAdd(&sums[o+j], ps[j]);
        atomicAdd(&sums[512+o+j], qs[j]);
      }
    }
  }
  // ---- C store: 4 contiguous o per lane -> ushort4 -------------------------
  #pragma unroll
  for (int ni = 0; ni < 4; ++ni) {
    size_t p = p0 + wr*64 + ni*16 + l15;
    #pragma unroll
    for (int mi = 0; mi < 4; ++mi) {
      int o = o0 + wc*64 + mi*16 + l4*4;
      ushort4 v = make_ushort4(f2bf(acc[mi][ni][0]), f2bf(acc[mi][ni][1]),
                               f2bf(acc[mi][ni][2]), f2bf(acc[mi][ni][3]));
      *(ushort4*)(C + p*CO + o) = v;
    }
  }
}

__global__ void finalize_kernel(const float* __restrict__ sums,
                                const float* __restrict__ g,
                                const float* __restrict__ bia,
                                float* __restrict__ ss) {
  int c = blockIdx.x*256 + threadIdx.x;
  if (c >= 512) return;
  const float invN = 1.f / (float)P_TOT;
  float mean = sums[c] * invN;
  float var  = sums[512+c] * invN - mean*mean;
  float sc = g[c] * rsqrtf(var + 1e-5f);
  ss[c] = sc;
  ss[512+c] = bia[c] - mean*sc;
}

// ============ GEMM2: A = relu(affine(h1_raw)) fused in staging ===============
// Same structure as gemm1; X reg-staged (global -> BN1+ReLU -> swizzled ds_write)
__global__ __launch_bounds__(256) void gemm2_kernel(
    const unsigned short* __restrict__ h1,    // (P, 512) raw
    const unsigned short* __restrict__ Bw,    // (512, 512)
    const float* __restrict__ ss,             // BN1 scale/shift (1024 f32)
    float* __restrict__ sums,                 // BN2 stats
    float* __restrict__ pmax,                 // (4096, 512)
    float* __restrict__ pmin)
{
  __shared__ unsigned short Ws_[128*32];
  __shared__ unsigned short Xs[128*32];
  __shared__ float ssl[1024];
  int bx = blockIdx.x;
  int lg = (bx & 7)*512 + (bx >> 3);
  int o0 = (lg & 3) * 128;
  size_t p0 = (size_t)(lg >> 2) * 128;
  int t = threadIdx.x;
  int w = t >> 6, lane = t & 63;
  int wr = w >> 1, wc = w & 1;
  int l15 = lane & 15, l4 = lane >> 4;

  // stage ss into LDS once
  *(float4*)(ssl + t*4) = *(const float4*)(ss + t*4);

  int sl = (lane & 3) ^ ((lane >> 3) & 3);    // swizzled slot (W source / X dest)
  const unsigned short* xsrc[2];              // linear-slot source (reg-staged)
  const unsigned short* wsrc[2];
  int xdst[2];                                // swizzled LDS elem offset for X
  #pragma unroll
  for (int cc = 0; cc < 2; ++cc) {
    int c = 2*w + cc;
    int row = 16*c + (lane >> 2);
    xsrc[cc] = h1 + (p0 + row) * 512 + (lane & 3)*8;
    wsrc[cc] = Bw + (size_t)(o0 + row) * 512 + sl*8;
    xdst[cc] = row*32 + sl*8;
  }
  int csel = (lane & 3) * 8;                  // channel sub-block for transform

  f32x4 acc[4][4];
  f32x4 zf = {0.f, 0.f, 0.f, 0.f};
  #pragma unroll
  for (int mi = 0; mi < 4; ++mi)
    #pragma unroll
    for (int ni = 0; ni < 4; ++ni) acc[mi][ni] = zf;

  int xm = (l15 >> 1) & 3;
  __syncthreads();                            // ssl visible to all

  for (int k0 = 0; k0 < CIN; k0 += 32) {
    uint4 xv[2];
    #pragma unroll
    for (int cc = 0; cc < 2; ++cc) {
      int c = 2*w + cc;
      load_lds16(wsrc[cc] + k0, (char*)Ws_ + c*1024);
      xv[cc] = *(const uint4*)(xsrc[cc] + k0);
    }
    // BN1 scale/shift for channels k0+csel .. +7
    float4 sa = *(const float4*)(ssl + k0 + csel);
    float4 sb = *(const float4*)(ssl + k0 + csel + 4);
    float4 ha = *(const float4*)(ssl + 512 + k0 + csel);
    float4 hb = *(const float4*)(ssl + 512 + k0 + csel + 4);
    float sc[8] = {sa.x,sa.y,sa.z,sa.w,sb.x,sb.y,sb.z,sb.w};
    float sh[8] = {ha.x,ha.y,ha.z,ha.w,hb.x,hb.y,hb.z,hb.w};
    #pragma unroll
    for (int cc = 0; cc < 2; ++cc) {
      unsigned int wv[4] = {xv[cc].x, xv[cc].y, xv[cc].z, xv[cc].w};
      unsigned int rv[4];
      #pragma unroll
      for (int j = 0; j < 4; ++j) {
        float f0 = fmaxf(fmaf(bf2f((unsigned short)(wv[j] & 0xffffu)), sc[2*j],   sh[2*j]),   0.f);
        float f1 = fmaxf(fmaf(bf2f((unsigned short)(wv[j] >> 16)),     sc[2*j+1], sh[2*j+1]), 0.f);
        rv[j] = (unsigned int)f2bf(f0) | ((unsigned int)f2bf(f1) << 16);
      }
      *(uint4*)(&Xs[xdst[cc]]) = make_uint4(rv[0], rv[1], rv[2], rv[3]);
    }
    __syncthreads();
    int cA = (l4 ^ xm) * 8;
    short8 af[4], bfr[4];
    #pragma unroll
    for (int mi = 0; mi < 4; ++mi)
      af[mi] = *(const short8*)(Ws_ + (wc*64 + mi*16 + l15)*32 + cA);
    #pragma unroll
    for (int ni = 0; ni < 4; ++ni)
      bfr[ni] = *(const short8*)(Xs + (wr*64 + ni*16 + l15)*32 + cA);
    #pragma unroll
    for (int mi = 0; mi < 4; ++mi)
      #pragma unroll
      for (int ni = 0; ni < 4; ++ni)
        acc[mi][ni] = __builtin_amdgcn_mfma_f32_16x16x32_bf16(af[mi], bfr[ni], acc[mi][ni], 0, 0, 0);
    __syncthreads();
  }

  // ---- BN2 stats -----------------------------------------------------------
  #pragma unroll
  for (int mi = 0; mi < 4; ++mi) {
    float ps[4] = {0.f,0.f,0.f,0.f}, qs[4] = {0.f,0.f,0.f,0.f};
    #pragma unroll
    for (int ni = 0; ni < 4; ++ni)
      #pragma unroll
      for (int j = 0; j < 4; ++j) { float v = acc[mi][ni][j]; ps[j] += v; qs[j] += v*v; }
    #pragma unroll
    for (int j = 0; j < 4; ++j) {
      #pragma unroll
      for (int m = 1; m < 16; m <<= 1) {
        ps[j] += __shfl_xor(ps[j], m);
        qs[j] += __shfl_xor(qs[j], m);
      }
    }
    if (l15 == 0) {
      int o = o0 + wc*64 + mi*16 + l4*4;
      #pragma unroll
      for (int j = 0; j < 4; ++j) {
        atomicAdd(&sums[o+j], ps[j]);
        atomicAdd(&sums[512+o+j], qs[j]);
      }
    }
  }
  // ---- max/min pool over S=32 ----------------------------------------------
  #pragma unroll
  for (int mi = 0; mi < 4; ++mi) {
    #pragma unroll
    for (int h = 0; h < 2; ++h) {
      float mx[4], mn[4];
      #pragma unroll
      for (int j = 0; j < 4; ++j) { mx[j] = -3.4e38f; mn[j] = 3.4e38f; }
      #pragma unroll
      for (int ni = 2*h; ni < 2*h + 2; ++ni)
        #pragma unroll
        for (int j = 0; j < 4; ++j) {
          float v = acc[mi][ni][j];
          mx[j] = fmaxf(mx[j], v); mn[j] = fminf(mn[j], v);
        }
      #pragma unroll
      for (int j = 0; j < 4; ++j) {
        #pragma unroll
        for (int m = 1; m < 16; m <<= 1) {
          mx[j] = fmaxf(mx[j], __shfl_xor(mx[j], m));
          mn[j] = fminf(mn[j], __shfl_xor(mn[j], m));
        }
      }
      if (l15 == 0) {
        size_t seed = (p0 >> 5) + wr*2 + h;
        int o = o0 + wc*64 + mi*16 + l4*4;
        *(float4*)(pmax + seed*512 + o) = make_float4(mx[0], mx[1], mx[2], mx[3]);
        *(float4*)(pmin + seed*512 + o) = make_float4(mn[0], mn[1], mn[2], mn[3]);
      }
    }
  }
}

// ---------------- final: affine+relu on pooled, transpose to (B,512,M) ------
__global__ void final_transpose(const float* __restrict__ pmax,
                                const float* __restrict__ pmin,
                                const float* __restrict__ ss,
                                float* __restrict__ out) {
  __shared__ float tile[64][65];
  int b = blockIdx.z, ob = blockIdx.y, mb = blockIdx.x;
  int t = threadIdx.x, tr = t >> 6, tc = t & 63;
  #pragma unroll
  for (int j = 0; j < 16; ++j) {
    int m = mb*64 + j*4 + tr;
    int o = ob*64 + tc;
    float sc = ss[o], sh = ss[512+o];
    size_t pi = (((size_t)b << 10) + m)*512 + o;
    float v = (sc >= 0.f) ? pmax[pi] : pmin[pi];
    tile[j*4+tr][tc] = fmaxf(fmaf(v, sc, sh), 0.f);
  }
  __syncthreads();
  #pragma unroll
  for (int j = 0; j < 16; ++j) {
    int o = ob*64 + j*4 + tr;
    out[((size_t)b*512 + o)*1024 + mb*64 + tc] = tile[tc][j*4+tr];
  }
}

extern "C" void kernel_launch(void* const* d_in, const int* in_sizes, int n_in,
                              void* d_out, int out_size, void* d_ws, size_t ws_size,
                              hipStream_t stream) {
  const float* xyz   = (const float*)d_in[0];
  const float* feats = (const float*)d_in[1];
  const float* rot   = (const float*)d_in[2];
  const float* W1    = (const float*)d_in[3];
  const float* g1    = (const float*)d_in[4];
  const float* b1    = (const float*)d_in[5];
  const float* W2    = (const float*)d_in[6];
  const float* g2    = (const float*)d_in[7];
  const float* b2    = (const float*)d_in[8];
  float* out = (float*)d_out;
  char* wsb = (char*)d_ws;

  const size_t OFF_IDX    = 0;
  const size_t OFF_TAIL   = OFF_IDX    + (size_t)P_TOT*4;
  const size_t OFF_FEATST = OFF_TAIL   + (size_t)P_TOT*32*2;
  const size_t OFF_W1B    = OFF_FEATST + (size_t)BATCH*NPTS*CIN*2;
  const size_t OFF_W2B    = OFF_W1B    + (size_t)CO*K1*2;
  const size_t OFF_STATS  = OFF_W2B    + (size_t)CO*CIN*2;
  const size_t OFF_PMAX   = OFF_STATS  + 16384;
  const size_t OFF_PMIN   = OFF_PMAX   + (size_t)BATCH*NPTS*CO*4;
  const size_t OFF_H1     = OFF_PMIN   + (size_t)BATCH*NPTS*CO*4;
  const size_t WS_NEED    = OFF_H1     + (size_t)P_TOT*CO*2;   // ~158 MiB (proven fit)

  if (ws_size < WS_NEED) return;   // diagnostic guard

  int* idx             = (int*)(wsb + OFF_IDX);
  unsigned short* tail = (unsigned short*)(wsb + OFF_TAIL);
  unsigned short* fT   = (unsigned short*)(wsb + OFF_FEATST);
  unsigned short* w1b  = (unsigned short*)(wsb + OFF_W1B);
  unsigned short* w2b  = (unsigned short*)(wsb + OFF_W2B);
  float* stats         = (float*)(wsb + OFF_STATS);
  float* sums1 = stats;
  float* ss1   = stats + 1024;
  float* sums2 = stats + 2048;
  float* ss2   = stats + 3072;
  float* pmax          = (float*)(wsb + OFF_PMAX);
  float* pmin          = (float*)(wsb + OFF_PMIN);
  unsigned short* h1   = (unsigned short*)(wsb + OFF_H1);

  hipMemsetAsync(stats, 0, 16384, stream);

  transpose_feats<<<dim3(NPTS/64, CIN/64, BATCH), 256, 0, stream>>>(feats, fT);
  cyl_query_kernel<<<BATCH*NPTS, 64, 0, stream>>>(xyz, rot, idx, tail);
  build_w1<<<(CO*K1 + 255)/256, 256, 0, stream>>>(W1, w1b);
  build_w2<<<(CO*CIN + 255)/256, 256, 0, stream>>>(W2, w2b);

  gemm1_kernel<<<(P_TOT/128)*4, 256, 0, stream>>>(fT, tail, idx, w1b, h1, sums1);
  finalize_kernel<<<2, 256, 0, stream>>>(sums1, g1, b1, ss1);

  gemm2_kernel<<<(P_TOT/128)*4, 256, 0, stream>>>(h1, w2b, ss1, sums2, pmax, pmin);
  finalize_kernel<<<2, 256, 0, stream>>>(sums2, g2, b2, ss2);

  final_transpose<<<dim3(NPTS/64, CO/64, BATCH), 256, 0, stream>>>(pmax, pmin, ss2, out);
}

// Round 5
// 303.221 us; speedup vs baseline: 1.7978x; 1.7020x over previous
//
#include <hip/hip_runtime.h>
#include <hip/hip_bf16.h>
#include <stdint.h>

#define BATCH 4
#define NPTS  1024
#define CIN   512
#define NS    32
#define P_TOT (BATCH*NPTS*NS)      /* 131072 */
#define K1    544                  /* 512 + 32 tail */
#define CO    512
#define RADIUS_F 0.05f
#define HMIN_F  (-0.02f)
#define HMAX_F  (0.04f)

typedef __attribute__((ext_vector_type(8))) short short8;
typedef __attribute__((ext_vector_type(4))) float f32x4;

__device__ __forceinline__ unsigned short f2bf(float f) {
  unsigned int x = __float_as_uint(f);
  x = x + 0x7fffu + ((x >> 16) & 1u);   // RNE
  return (unsigned short)(x >> 16);
}
__device__ __forceinline__ float bf2f(unsigned short u) {
  return __uint_as_float(((unsigned int)u) << 16);
}
__device__ __forceinline__ void load_lds16(const void* g, void* l) {
  __builtin_amdgcn_global_load_lds((const __attribute__((address_space(1))) void*)g,
                                   (__attribute__((address_space(3))) void*)l, 16, 0, 0);
}

// ---------------- cylinder query: idx + local coords into tail[p][0..31] ----
__global__ void cyl_query_kernel(const float* __restrict__ xyz,
                                 const float* __restrict__ rot,
                                 int* __restrict__ idxout,
                                 unsigned short* __restrict__ tail) {
  int bm = blockIdx.x;             // b*1024 + m
  int b = bm >> 10;
  int lane = threadIdx.x;          // 64 threads = 1 wave
  const float* ctr = xyz + (size_t)bm * 3;
  float cx = ctr[0], cy = ctr[1], cz = ctr[2];
  const float* R = rot + (size_t)bm * 9;
  float r00=R[0],r01=R[1],r02=R[2],r10=R[3],r11=R[4],r12=R[5],r20=R[6],r21=R[7],r22=R[8];
  __shared__ int sidx[32];
  int taken = 0;
  for (int base = 0; base < NPTS && taken < NS; base += 64) {
    int n = base + lane;
    const float* p = xyz + ((size_t)b * NPTS + n) * 3;
    float dx = p[0]-cx, dy = p[1]-cy, dz = p[2]-cz;
    float rx = dx*r00 + dy*r10 + dz*r20;
    float ry = dx*r01 + dy*r11 + dz*r21;
    float rz = dx*r02 + dy*r12 + dz*r22;
    bool ok = (ry*ry + rz*rz < RADIUS_F*RADIUS_F) && (rx > HMIN_F) && (rx < HMAX_F);
    unsigned long long bal = __ballot(ok);
    if (ok) {
      int slot = taken + __popcll(bal & ((1ull << lane) - 1ull));
      if (slot < NS) sidx[slot] = n;
    }
    taken += __popcll(bal);
  }
  __syncthreads();
  int filled = taken < NS ? taken : NS;
  if (lane < NS) {
    int nsel = (lane < filled) ? sidx[lane] : sidx[0];
    size_t p0 = (size_t)bm * NS + lane;
    idxout[p0] = nsel;
    const float* pn = xyz + ((size_t)b * NPTS + nsel) * 3;
    float dx = pn[0]-cx, dy = pn[1]-cy, dz = pn[2]-cz;
    const float inv = 1.0f / RADIUS_F;
    float rx = (dx*r00 + dy*r10 + dz*r20) * inv;
    float ry = (dx*r01 + dy*r11 + dz*r21) * inv;
    float rz = (dx*r02 + dy*r12 + dz*r22) * inv;
    unsigned short* row = tail + p0 * 32;
    row[0] = f2bf(rx); row[1] = f2bf(ry); row[2] = f2bf(rz);
    #pragma unroll
    for (int k = 3; k < 32; ++k) row[k] = 0;
  }
}

// ---------------- transpose feats (B,C,N) fp32 -> (B,N,C) bf16 --------------
__global__ void transpose_feats(const float* __restrict__ feats,
                                unsigned short* __restrict__ featsT) {
  __shared__ float tile[64][65];
  int b = blockIdx.z, cb = blockIdx.y, nb = blockIdx.x;
  int t = threadIdx.x, tr = t >> 6, tc = t & 63;
  #pragma unroll
  for (int j = 0; j < 16; ++j) {
    int c = cb*64 + j*4 + tr;
    tile[j*4+tr][tc] = feats[((size_t)b*CIN + c)*NPTS + nb*64 + tc];
  }
  __syncthreads();
  #pragma unroll
  for (int j = 0; j < 16; ++j) {
    int n = nb*64 + j*4 + tr;
    featsT[((size_t)b*NPTS + n)*CIN + cb*64 + tc] = f2bf(tile[tc][j*4+tr]);
  }
}

// ---------------- weight conversion -----------------------------------------
__global__ void build_w1(const float* __restrict__ W1, unsigned short* __restrict__ w1b) {
  int i = blockIdx.x*256 + threadIdx.x;
  if (i >= CO*K1) return;
  int o = i / K1, k = i % K1;
  float v = 0.f;
  if (k < 512) v = W1[o*515 + 3 + k];
  else if (k < 515) v = W1[o*515 + (k - 512)];
  w1b[i] = f2bf(v);
}
__global__ void build_w2(const float* __restrict__ W2, unsigned short* __restrict__ w2b) {
  int i = blockIdx.x*256 + threadIdx.x;
  if (i < CO*CIN) w2b[i] = f2bf(W2[i]);
}

// ============ GEMM1 (round-2 verbatim): gathered A x W1^T ====================
// C[p][o] = sum_k A[p][k]*B[o][k]; also per-channel atomic sum/sumsq of acc.
__global__ __launch_bounds__(256) void gemm1_kernel(
    const unsigned short* __restrict__ fT,    // (B*N, 512) bf16
    const unsigned short* __restrict__ tail,  // (P, 32) bf16
    const int* __restrict__ idx,              // (P)
    const unsigned short* __restrict__ Bw,    // (512, 544) bf16
    unsigned short* __restrict__ C,           // (P, 512) bf16 (raw, pre-BN)
    float* __restrict__ sums)                 // [0..511]=sum, [512..1023]=sumsq
{
  __shared__ unsigned short As[128*32];
  __shared__ unsigned short Bs[128*32];
  int bx = blockIdx.x;
  int ob = bx & 3;
  size_t p0 = (size_t)(bx >> 2) * 128;
  int o0 = ob * 128;
  int t = threadIdx.x;
  int w = t >> 6, lane = t & 63;
  int wr = w >> 1, wc = w & 1;
  int l15 = lane & 15, l4 = lane >> 4;
  f32x4 acc[4][4];
  f32x4 zf = {0.f, 0.f, 0.f, 0.f};
  #pragma unroll
  for (int mi = 0; mi < 4; ++mi)
    #pragma unroll
    for (int ni = 0; ni < 4; ++ni) acc[mi][ni] = zf;

  int c0 = 2*w;
  int srow = lane >> 2;         // staged row within chunk (0..15)
  int scole = (lane & 3) * 8;   // element offset within 32-wide k-slab

  // per-chunk gather bases (row assignment is constant across the K loop)
  const unsigned short* abase[2];
  const unsigned short* tbase[2];
  #pragma unroll
  for (int cc = 0; cc < 2; ++cc) {
    int row = 16*(c0+cc) + srow;
    size_t p = p0 + row;
    int b = (int)(p >> 15);
    int n = idx[p];
    abase[cc] = fT + (((size_t)b << 10) + n) * (size_t)CIN + scole;
    tbase[cc] = tail + p * 32 + scole;
  }

  for (int k0 = 0; k0 < K1; k0 += 32) {
    #pragma unroll
    for (int cc = 0; cc < 2; ++cc) {
      int c = c0 + cc;
      const unsigned short* gA = (k0 < CIN) ? (abase[cc] + k0) : tbase[cc];
      load_lds16(gA, (char*)As + c*1024);
      int row = 16*c + srow;
      const unsigned short* gB = Bw + (size_t)(o0 + row)*K1 + k0 + scole;
      load_lds16(gB, (char*)Bs + c*1024);
    }
    __syncthreads();
    short8 af[4], bfr[4];
    #pragma unroll
    for (int mi = 0; mi < 4; ++mi)
      af[mi] = *(const short8*)(As + (wr*64 + mi*16 + l15)*32 + l4*8);
    #pragma unroll
    for (int ni = 0; ni < 4; ++ni)
      bfr[ni] = *(const short8*)(Bs + (wc*64 + ni*16 + l15)*32 + l4*8);
    #pragma unroll
    for (int mi = 0; mi < 4; ++mi)
      #pragma unroll
      for (int ni = 0; ni < 4; ++ni)
        acc[mi][ni] = __builtin_amdgcn_mfma_f32_16x16x32_bf16(af[mi], bfr[ni], acc[mi][ni], 0, 0, 0);
    __syncthreads();
  }

  // epilogue: per-channel stats (sum, sumsq) via shfl + atomics
  #pragma unroll
  for (int ni = 0; ni < 4; ++ni) {
    float s = 0.f, q = 0.f;
    #pragma unroll
    for (int mi = 0; mi < 4; ++mi)
      #pragma unroll
      for (int j = 0; j < 4; ++j) { float v = acc[mi][ni][j]; s += v; q += v*v; }
    s += __shfl_xor(s, 16); q += __shfl_xor(q, 16);
    s += __shfl_xor(s, 32); q += __shfl_xor(q, 32);
    if (l4 == 0) {
      int c = o0 + wc*64 + ni*16 + l15;
      atomicAdd(&sums[c], s);
      atomicAdd(&sums[512 + c], q);
    }
  }
  // C store (raw bf16)
  #pragma unroll
  for (int mi = 0; mi < 4; ++mi)
    #pragma unroll
    for (int ni = 0; ni < 4; ++ni)
      #pragma unroll
      for (int j = 0; j < 4; ++j) {
        size_t p = p0 + wr*64 + mi*16 + l4*4 + j;
        int o = o0 + wc*64 + ni*16 + l15;
        C[p*CO + o] = f2bf(acc[mi][ni][j]);
      }
}

__global__ void finalize_kernel(const float* __restrict__ sums,
                                const float* __restrict__ g,
                                const float* __restrict__ bia,
                                float* __restrict__ ss) {
  int c = blockIdx.x*256 + threadIdx.x;
  if (c >= 512) return;
  const float invN = 1.f / (float)P_TOT;
  float mean = sums[c] * invN;
  float var  = sums[512+c] * invN - mean*mean;
  float sc = g[c] * rsqrtf(var + 1e-5f);
  ss[c] = sc;
  ss[512+c] = bia[c] - mean*sc;
}

// ============ GEMM2 (round-2 structure): A = relu(affine(h1)) in staging ====
// ONLY delta vs round 2: A-tile is reg-loaded (prefetched), BN1+ReLU applied
// in registers, then ds_write_b128 to the SAME linear LDS bytes. W staging,
// barriers, fragment reads, MFMA, stats and pool epilogues are r2-verbatim.
__global__ __launch_bounds__(256) void gemm2_kernel(
    const unsigned short* __restrict__ A,     // (P, 512) bf16 RAW (pre-BN1)
    const unsigned short* __restrict__ Bw,    // (512, 512) bf16
    const float* __restrict__ ss,             // BN1 scale/shift (1024 f32)
    float* __restrict__ sums,                 // [0..511]=sum, [512..1023]=sumsq
    float* __restrict__ pmax,                 // (4096, 512) f32
    float* __restrict__ pmin)
{
  __shared__ unsigned short As[128*32];
  __shared__ unsigned short Bs[128*32];
  __shared__ float ssl[1024];
  int bx = blockIdx.x;
  int ob = bx & 3;
  size_t p0 = (size_t)(bx >> 2) * 128;
  int o0 = ob * 128;
  int t = threadIdx.x;
  int w = t >> 6, lane = t & 63;
  int wr = w >> 1, wc = w & 1;
  int l15 = lane & 15, l4 = lane >> 4;
  f32x4 acc[4][4];
  f32x4 zf = {0.f, 0.f, 0.f, 0.f};
  #pragma unroll
  for (int mi = 0; mi < 4; ++mi)
    #pragma unroll
    for (int ni = 0; ni < 4; ++ni) acc[mi][ni] = zf;

  int c0 = 2*w;
  int srow = lane >> 2;
  int scole = (lane & 3) * 8;

  // stage BN1 scale/shift table into LDS (4 KB)
  *(float4*)(ssl + t*4) = *(const float4*)(ss + t*4);

  const unsigned short* aptr[2];
  const unsigned short* bptr[2];
  #pragma unroll
  for (int cc = 0; cc < 2; ++cc) {
    int row = 16*(c0+cc) + srow;
    aptr[cc] = A + (p0 + row)*(size_t)CIN + scole;
    bptr[cc] = Bw + (size_t)(o0 + row)*CIN + scole;
  }

  // prefetch A-regs for tile 0 (T14 issue-early)
  uint4 xv[2];
  xv[0] = *(const uint4*)(aptr[0]);
  xv[1] = *(const uint4*)(aptr[1]);
  __syncthreads();                 // ssl visible before first transform

  for (int k0 = 0; k0 < CIN; k0 += 32) {
    // stage W tile (async global->LDS, drained by the barrier)
    #pragma unroll
    for (int cc = 0; cc < 2; ++cc)
      load_lds16(bptr[cc] + k0, (char*)Bs + (c0+cc)*1024);
    // transform current A-regs (BN1 affine + ReLU, fp32) -> LDS
    {
      float sc[8], sh[8];
      #pragma unroll
      for (int e = 0; e < 8; ++e) {
        sc[e] = ssl[k0 + scole + e];
        sh[e] = ssl[512 + k0 + scole + e];
      }
      #pragma unroll
      for (int cc = 0; cc < 2; ++cc) {
        unsigned int wv[4] = {xv[cc].x, xv[cc].y, xv[cc].z, xv[cc].w};
        unsigned int rv[4];
        #pragma unroll
        for (int j = 0; j < 4; ++j) {
          float f0 = fmaxf(fmaf(bf2f((unsigned short)(wv[j] & 0xffffu)), sc[2*j],   sh[2*j]),   0.f);
          float f1 = fmaxf(fmaf(bf2f((unsigned short)(wv[j] >> 16)),     sc[2*j+1], sh[2*j+1]), 0.f);
          rv[j] = (unsigned int)f2bf(f0) | ((unsigned int)f2bf(f1) << 16);
        }
        *(uint4*)((char*)As + (c0+cc)*1024 + lane*16) = make_uint4(rv[0], rv[1], rv[2], rv[3]);
      }
    }
    // prefetch next A-regs (overlaps this tile's compute)
    if (k0 + 32 < CIN) {
      xv[0] = *(const uint4*)(aptr[0] + k0 + 32);
      xv[1] = *(const uint4*)(aptr[1] + k0 + 32);
    }
    __syncthreads();
    short8 af[4], bfr[4];
    #pragma unroll
    for (int mi = 0; mi < 4; ++mi)
      af[mi] = *(const short8*)(As + (wr*64 + mi*16 + l15)*32 + l4*8);
    #pragma unroll
    for (int ni = 0; ni < 4; ++ni)
      bfr[ni] = *(const short8*)(Bs + (wc*64 + ni*16 + l15)*32 + l4*8);
    #pragma unroll
    for (int mi = 0; mi < 4; ++mi)
      #pragma unroll
      for (int ni = 0; ni < 4; ++ni)
        acc[mi][ni] = __builtin_amdgcn_mfma_f32_16x16x32_bf16(af[mi], bfr[ni], acc[mi][ni], 0, 0, 0);
    __syncthreads();
  }

  // stats (r2-verbatim)
  #pragma unroll
  for (int ni = 0; ni < 4; ++ni) {
    float s = 0.f, q = 0.f;
    #pragma unroll
    for (int mi = 0; mi < 4; ++mi)
      #pragma unroll
      for (int j = 0; j < 4; ++j) { float v = acc[mi][ni][j]; s += v; q += v*v; }
    s += __shfl_xor(s, 16); q += __shfl_xor(q, 16);
    s += __shfl_xor(s, 32); q += __shfl_xor(q, 32);
    if (l4 == 0) {
      int c = o0 + wc*64 + ni*16 + l15;
      atomicAdd(&sums[c], s);
      atomicAdd(&sums[512 + c], q);
    }
  }
  // max/min pool over S=32 (r2-verbatim)
  #pragma unroll
  for (int ni = 0; ni < 4; ++ni) {
    #pragma unroll
    for (int h = 0; h < 2; ++h) {
      float mx = -3.4e38f, mn = 3.4e38f;
      #pragma unroll
      for (int mi = 2*h; mi < 2*h + 2; ++mi)
        #pragma unroll
        for (int j = 0; j < 4; ++j) {
          float v = acc[mi][ni][j];
          mx = fmaxf(mx, v); mn = fminf(mn, v);
        }
      mx = fmaxf(mx, __shfl_xor(mx, 16)); mn = fminf(mn, __shfl_xor(mn, 16));
      mx = fmaxf(mx, __shfl_xor(mx, 32)); mn = fminf(mn, __shfl_xor(mn, 32));
      if (l4 == 0) {
        size_t bm = (p0 >> 5) + 2*wr + h;
        int o = o0 + wc*64 + ni*16 + l15;
        pmax[bm*512 + o] = mx;
        pmin[bm*512 + o] = mn;
      }
    }
  }
}

// ---------------- final: affine+relu on pooled, transpose to (B,512,M) ------
__global__ void final_transpose(const float* __restrict__ pmax,
                                const float* __restrict__ pmin,
                                const float* __restrict__ ss,
                                float* __restrict__ out) {
  __shared__ float tile[64][65];
  int b = blockIdx.z, ob = blockIdx.y, mb = blockIdx.x;
  int t = threadIdx.x, tr = t >> 6, tc = t & 63;
  #pragma unroll
  for (int j = 0; j < 16; ++j) {
    int m = mb*64 + j*4 + tr;
    int o = ob*64 + tc;
    float sc = ss[o], sh = ss[512+o];
    size_t pi = (((size_t)b << 10) + m)*512 + o;
    float v = (sc >= 0.f) ? pmax[pi] : pmin[pi];
    tile[j*4+tr][tc] = fmaxf(fmaf(v, sc, sh), 0.f);
  }
  __syncthreads();
  #pragma unroll
  for (int j = 0; j < 16; ++j) {
    int o = ob*64 + j*4 + tr;
    out[((size_t)b*512 + o)*1024 + mb*64 + tc] = tile[tc][j*4+tr];
  }
}

extern "C" void kernel_launch(void* const* d_in, const int* in_sizes, int n_in,
                              void* d_out, int out_size, void* d_ws, size_t ws_size,
                              hipStream_t stream) {
  const float* xyz   = (const float*)d_in[0];
  const float* feats = (const float*)d_in[1];
  const float* rot   = (const float*)d_in[2];
  const float* W1    = (const float*)d_in[3];
  const float* g1    = (const float*)d_in[4];
  const float* b1    = (const float*)d_in[5];
  const float* W2    = (const float*)d_in[6];
  const float* g2    = (const float*)d_in[7];
  const float* b2    = (const float*)d_in[8];
  float* out = (float*)d_out;
  char* wsb = (char*)d_ws;

  const size_t OFF_IDX    = 0;
  const size_t OFF_TAIL   = OFF_IDX    + (size_t)P_TOT*4;
  const size_t OFF_FEATST = OFF_TAIL   + (size_t)P_TOT*32*2;
  const size_t OFF_W1B    = OFF_FEATST + (size_t)BATCH*NPTS*CIN*2;
  const size_t OFF_W2B    = OFF_W1B    + (size_t)CO*K1*2;
  const size_t OFF_STATS  = OFF_W2B    + (size_t)CO*CIN*2;
  const size_t OFF_PMAX   = OFF_STATS  + 16384;
  const size_t OFF_PMIN   = OFF_PMAX   + (size_t)BATCH*NPTS*CO*4;
  const size_t OFF_H1     = OFF_PMIN   + (size_t)BATCH*NPTS*CO*4;
  const size_t WS_NEED    = OFF_H1     + (size_t)P_TOT*CO*2;   // ~158 MiB (proven fit)

  if (ws_size < WS_NEED) return;   // diagnostic guard

  int* idx             = (int*)(wsb + OFF_IDX);
  unsigned short* tail = (unsigned short*)(wsb + OFF_TAIL);
  unsigned short* fT   = (unsigned short*)(wsb + OFF_FEATST);
  unsigned short* w1b  = (unsigned short*)(wsb + OFF_W1B);
  unsigned short* w2b  = (unsigned short*)(wsb + OFF_W2B);
  float* stats         = (float*)(wsb + OFF_STATS);
  float* sums1 = stats;
  float* ss1   = stats + 1024;
  float* sums2 = stats + 2048;
  float* ss2   = stats + 3072;
  float* pmax          = (float*)(wsb + OFF_PMAX);
  float* pmin          = (float*)(wsb + OFF_PMIN);
  unsigned short* h1   = (unsigned short*)(wsb + OFF_H1);

  hipMemsetAsync(stats, 0, 16384, stream);

  transpose_feats<<<dim3(NPTS/64, CIN/64, BATCH), 256, 0, stream>>>(feats, fT);
  cyl_query_kernel<<<BATCH*NPTS, 64, 0, stream>>>(xyz, rot, idx, tail);
  build_w1<<<(CO*K1 + 255)/256, 256, 0, stream>>>(W1, w1b);
  build_w2<<<(CO*CIN + 255)/256, 256, 0, stream>>>(W2, w2b);

  gemm1_kernel<<<(P_TOT/128)*4, 256, 0, stream>>>(fT, tail, idx, w1b, h1, sums1);
  finalize_kernel<<<2, 256, 0, stream>>>(sums1, g1, b1, ss1);

  gemm2_kernel<<<(P_TOT/128)*4, 256, 0, stream>>>(h1, w2b, ss1, sums2, pmax, pmin);
  finalize_kernel<<<2, 256, 0, stream>>>(sums2, g2, b2, ss2);

  final_transpose<<<dim3(NPTS/64, CO/64, BATCH), 256, 0, stream>>>(pmax, pmin, ss2, out);
}